// Round 8
// baseline (293.434 us; speedup 1.0000x reference)
//
#include <hip/hip_runtime.h>
#include <hip/hip_fp16.h>

#define RES 512
#define NCH 32
#define HW (RES * RES)
#define PLANE_H_ELEMS (NCH * HW)     // half elements per transposed plane
#define NBUCKETS 4096                // 16x16x16 Morton voxel grid

typedef float vfloat4 __attribute__((ext_vector_type(4)));  // nontemporal-legal

// ---------------------------------------------------------------------------
// Morton bucket helpers
// ---------------------------------------------------------------------------
__device__ __forceinline__ unsigned spread3(unsigned x) {
    x &= 0x3FF;
    x = (x | (x << 16)) & 0x030000FF;
    x = (x | (x <<  8)) & 0x0300F00F;
    x = (x | (x <<  4)) & 0x030C30C3;
    x = (x | (x <<  2)) & 0x09249249;
    return x;
}
__device__ __forceinline__ unsigned bucket_of(float c0, float c1, float c2) {
    int bx = min(max((int)(c0 * 16.f), 0), 15);
    int by = min(max((int)(c1 * 16.f), 0), 15);
    int bz = min(max((int)(c2 * 16.f), 0), 15);
    return spread3(bx) | (spread3(by) << 1) | (spread3(bz) << 2);
}

// ---------------------------------------------------------------------------
// Tiny zero kernel for the histogram.
// ---------------------------------------------------------------------------
__global__ __launch_bounds__(256) void zero_hist(unsigned* __restrict__ hist) {
    hist[blockIdx.x * 256 + threadIdx.x] = 0u;
}

// ---------------------------------------------------------------------------
// Pre-pass: transpose (C,H,W) fp32 -> (H,W,C) fp16. LDS-tiled, coalesced.
// (verbatim from the passing round-7 kernel)
// ---------------------------------------------------------------------------
__global__ __launch_bounds__(256) void transpose_chw_hwc_h(
    const float* __restrict__ p0, const float* __restrict__ p1,
    const float* __restrict__ p2, __half2* __restrict__ dst_all)
{
    __shared__ float lds[64 * 33];
    int blk   = blockIdx.x;
    int t     = threadIdx.x;
    int plane = blk >> 12;
    int rem   = blk & 4095;
    int y     = rem >> 3;
    int xt    = (rem & 7) << 6;
    const float* src = (plane == 0) ? p0 : (plane == 1) ? p1 : p2;
    __half2* dst = dst_all + (size_t)plane * (PLANE_H_ELEMS / 2);

    #pragma unroll
    for (int k = 0; k < 8; ++k) {
        int idx = t + (k << 8);      // 0..2047
        int c   = idx >> 6;          // channel 0..31
        int xi  = idx & 63;          // x within tile
        lds[xi * 33 + c] = src[(size_t)c * HW + (size_t)y * RES + xt + xi];
    }
    __syncthreads();
    #pragma unroll
    for (int k = 0; k < 4; ++k) {
        int idx = t + (k << 8);      // 0..1023
        int xi  = idx >> 4;          // x within tile
        int cp  = idx & 15;          // channel pair
        __half2 h = __halves2half2(__float2half_rn(lds[xi * 33 + 2 * cp]),
                                   __float2half_rn(lds[xi * 33 + 2 * cp + 1]));
        dst[((size_t)(y * RES + xt + xi)) * 16 + cp] = h;
    }
}

// ---------------------------------------------------------------------------
// Counting sort pass 1: per-block LDS histogram -> global histogram.
// ---------------------------------------------------------------------------
__global__ __launch_bounds__(256) void hist_kernel(
    const float* __restrict__ x, int npts, unsigned* __restrict__ hist)
{
    __shared__ unsigned lh[NBUCKETS];
    int t = threadIdx.x;
    for (int i = t; i < NBUCKETS; i += 256) lh[i] = 0;
    __syncthreads();

    int per = (npts + gridDim.x - 1) / gridDim.x;
    int start = blockIdx.x * per;
    int end = min(npts, start + per);
    for (int i = start + t; i < end; i += 256) {
        float c0 = x[3 * i + 0], c1 = x[3 * i + 1], c2 = x[3 * i + 2];
        atomicAdd(&lh[bucket_of(c0, c1, c2)], 1u);
    }
    __syncthreads();
    for (int i = t; i < NBUCKETS; i += 256)
        if (lh[i]) atomicAdd(&hist[i], lh[i]);
}

// ---------------------------------------------------------------------------
// Counting sort pass 2: exclusive scan of 4096 counts. One block, 1024 thr.
// ---------------------------------------------------------------------------
__global__ __launch_bounds__(1024) void scan_kernel(
    const unsigned* __restrict__ hist, unsigned* __restrict__ offs)
{
    __shared__ unsigned sd[1024];
    int t = threadIdx.x;
    unsigned h0 = hist[4 * t + 0], h1 = hist[4 * t + 1];
    unsigned h2 = hist[4 * t + 2], h3 = hist[4 * t + 3];
    sd[t] = h0 + h1 + h2 + h3;
    __syncthreads();
    for (int d = 1; d < 1024; d <<= 1) {
        unsigned v = (t >= d) ? sd[t - d] : 0u;
        __syncthreads();
        sd[t] += v;
        __syncthreads();
    }
    unsigned excl = (t > 0) ? sd[t - 1] : 0u;
    offs[4 * t + 0] = excl;
    offs[4 * t + 1] = excl + h0;
    offs[4 * t + 2] = excl + h0 + h1;
    offs[4 * t + 3] = excl + h0 + h1 + h2;
}

// ---------------------------------------------------------------------------
// Counting sort pass 3: scatter (c0,c1,c2,orig_idx) into bucket order.
// ---------------------------------------------------------------------------
__global__ __launch_bounds__(256) void scatter_kernel(
    const float* __restrict__ x, int npts, unsigned* __restrict__ offs,
    float4* __restrict__ sorted)
{
    int i = blockIdx.x * 256 + threadIdx.x;
    if (i >= npts) return;
    float c0 = x[3 * i + 0], c1 = x[3 * i + 1], c2 = x[3 * i + 2];
    unsigned b = bucket_of(c0, c1, c2);
    unsigned pos = atomicAdd(&offs[b], 1u);
    sorted[pos] = make_float4(c0, c1, c2, __int_as_float(i));
}

// ---------------------------------------------------------------------------
// Main sampler, 2 points per thread for doubled MLP. 8 lanes per point-slot;
// lane q owns channels [4q,4q+4) (proven uint2 decode). Per thread: phase-1
// address/weight math for points s and s+32, then ALL 24 corner gathers
// issued back-to-back, then both decodes, then two NT stores.
// ---------------------------------------------------------------------------
__global__ __launch_bounds__(256, 4) void sample_sorted_h2(
    const float4* __restrict__ sorted, const __half* __restrict__ planes,
    float* __restrict__ out, int npts, int nb_q, int nb_r)
{
    int bid = blockIdx.x;
    int xcd = bid & 7;
    int j   = bid >> 3;
    int chunk = (xcd < nb_r ? xcd * (nb_q + 1) : nb_r * (nb_q + 1) + (xcd - nb_r) * nb_q) + j;

    int g = threadIdx.x >> 3;                  // point-group 0..31
    int q = threadIdx.x & 7;                   // channel quad
    int s0 = chunk * 64 + g;                   // 64 points per block
    int s1 = s0 + 32;
    if (s0 >= npts) return;
    bool hasB = (s1 < npts);

    float4 pA = sorted[s0];
    float4 pB = sorted[hasB ? s1 : s0];
    int bA = __float_as_int(pA.w);
    int bB = __float_as_int(pB.w);

    const float gxsA[3] = { pA.x, pA.x, pA.y };
    const float gysA[3] = { pA.y, pA.z, pA.z };
    const float gxsB[3] = { pB.x, pB.x, pB.y };
    const float gysB[3] = { pB.y, pB.z, pB.z };

    // Phase 1: addresses + weights for both points, all planes.
    const __half* baseA[3]; float wA00[3], wA01[3], wA10[3], wA11[3];
    const __half* baseB[3]; float wB00[3], wB01[3], wB10[3], wB11[3];
    #pragma unroll
    for (int pl = 0; pl < 3; ++pl) {
        float ix = fmaf(gxsA[pl], 255.5f, 255.5f);
        float iy = fmaf(gysA[pl], 255.5f, 255.5f);
        float xf = floorf(ix), yf = floorf(iy);
        float wx = ix - xf,  wy = iy - yf;
        int x0 = min(max((int)xf, 0), RES - 2);
        int y0 = min(max((int)yf, 0), RES - 2);
        baseA[pl] = planes + (size_t)pl * PLANE_H_ELEMS
                  + (size_t)(y0 * RES + x0) * NCH + q * 4;
        float omx = 1.f - wx, omy = 1.f - wy;
        wA00[pl] = omx * omy; wA01[pl] = wx * omy;
        wA10[pl] = omx * wy;  wA11[pl] = wx * wy;
    }
    #pragma unroll
    for (int pl = 0; pl < 3; ++pl) {
        float ix = fmaf(gxsB[pl], 255.5f, 255.5f);
        float iy = fmaf(gysB[pl], 255.5f, 255.5f);
        float xf = floorf(ix), yf = floorf(iy);
        float wx = ix - xf,  wy = iy - yf;
        int x0 = min(max((int)xf, 0), RES - 2);
        int y0 = min(max((int)yf, 0), RES - 2);
        baseB[pl] = planes + (size_t)pl * PLANE_H_ELEMS
                  + (size_t)(y0 * RES + x0) * NCH + q * 4;
        float omx = 1.f - wx, omy = 1.f - wy;
        wB00[pl] = omx * omy; wB01[pl] = wx * omy;
        wB10[pl] = omx * wy;  wB11[pl] = wx * wy;
    }

    // Phase 2: issue all 24 corner gathers back-to-back (MLP).
    uint2 uA00[3], uA01[3], uA10[3], uA11[3];
    uint2 uB00[3], uB01[3], uB10[3], uB11[3];
    #pragma unroll
    for (int pl = 0; pl < 3; ++pl) {
        uA00[pl] = *(const uint2*)(baseA[pl]);
        uA01[pl] = *(const uint2*)(baseA[pl] + NCH);
        uA10[pl] = *(const uint2*)(baseA[pl] + RES * NCH);
        uA11[pl] = *(const uint2*)(baseA[pl] + RES * NCH + NCH);
    }
    #pragma unroll
    for (int pl = 0; pl < 3; ++pl) {
        uB00[pl] = *(const uint2*)(baseB[pl]);
        uB01[pl] = *(const uint2*)(baseB[pl] + NCH);
        uB10[pl] = *(const uint2*)(baseB[pl] + RES * NCH);
        uB11[pl] = *(const uint2*)(baseB[pl] + RES * NCH + NCH);
    }

    // Phase 3: decode + interpolate point A (proven r5/r7 math).
    float4 accA = make_float4(1.f, 1.f, 1.f, 1.f);
    #pragma unroll
    for (int pl = 0; pl < 3; ++pl) {
        float2 a00 = __half22float2(__builtin_bit_cast(__half2, uA00[pl].x));
        float2 b00 = __half22float2(__builtin_bit_cast(__half2, uA00[pl].y));
        float2 a01 = __half22float2(__builtin_bit_cast(__half2, uA01[pl].x));
        float2 b01 = __half22float2(__builtin_bit_cast(__half2, uA01[pl].y));
        float2 a10 = __half22float2(__builtin_bit_cast(__half2, uA10[pl].x));
        float2 b10 = __half22float2(__builtin_bit_cast(__half2, uA10[pl].y));
        float2 a11 = __half22float2(__builtin_bit_cast(__half2, uA11[pl].x));
        float2 b11 = __half22float2(__builtin_bit_cast(__half2, uA11[pl].y));

        float4 f;
        f.x = fmaf(a00.x, wA00[pl], fmaf(a01.x, wA01[pl], fmaf(a10.x, wA10[pl], a11.x * wA11[pl])));
        f.y = fmaf(a00.y, wA00[pl], fmaf(a01.y, wA01[pl], fmaf(a10.y, wA10[pl], a11.y * wA11[pl])));
        f.z = fmaf(b00.x, wA00[pl], fmaf(b01.x, wA01[pl], fmaf(b10.x, wA10[pl], b11.x * wA11[pl])));
        f.w = fmaf(b00.y, wA00[pl], fmaf(b01.y, wA01[pl], fmaf(b10.y, wA10[pl], b11.y * wA11[pl])));

        accA.x *= f.x; accA.y *= f.y; accA.z *= f.z; accA.w *= f.w;
    }
    vfloat4 accvA = { accA.x, accA.y, accA.z, accA.w };
    __builtin_nontemporal_store(accvA, (vfloat4*)(out + (size_t)bA * NCH + q * 4));

    // Phase 4: decode + interpolate point B.
    if (hasB) {
        float4 accB = make_float4(1.f, 1.f, 1.f, 1.f);
        #pragma unroll
        for (int pl = 0; pl < 3; ++pl) {
            float2 a00 = __half22float2(__builtin_bit_cast(__half2, uB00[pl].x));
            float2 b00 = __half22float2(__builtin_bit_cast(__half2, uB00[pl].y));
            float2 a01 = __half22float2(__builtin_bit_cast(__half2, uB01[pl].x));
            float2 b01 = __half22float2(__builtin_bit_cast(__half2, uB01[pl].y));
            float2 a10 = __half22float2(__builtin_bit_cast(__half2, uB10[pl].x));
            float2 b10 = __half22float2(__builtin_bit_cast(__half2, uB10[pl].y));
            float2 a11 = __half22float2(__builtin_bit_cast(__half2, uB11[pl].x));
            float2 b11 = __half22float2(__builtin_bit_cast(__half2, uB11[pl].y));

            float4 f;
            f.x = fmaf(a00.x, wB00[pl], fmaf(a01.x, wB01[pl], fmaf(a10.x, wB10[pl], a11.x * wB11[pl])));
            f.y = fmaf(a00.y, wB00[pl], fmaf(a01.y, wB01[pl], fmaf(a10.y, wB10[pl], a11.y * wB11[pl])));
            f.z = fmaf(b00.x, wB00[pl], fmaf(b01.x, wB01[pl], fmaf(b10.x, wB10[pl], b11.x * wB11[pl])));
            f.w = fmaf(b00.y, wB00[pl], fmaf(b01.y, wB01[pl], fmaf(b10.y, wB10[pl], b11.y * wB11[pl])));

            accB.x *= f.x; accB.y *= f.y; accB.z *= f.z; accB.w *= f.w;
        }
        vfloat4 accvB = { accB.x, accB.y, accB.z, accB.w };
        __builtin_nontemporal_store(accvB, (vfloat4*)(out + (size_t)bB * NCH + q * 4));
    }
}

// ---------------------------------------------------------------------------
// Fallback if d_ws is too small: sample directly from (C,H,W) fp32.
// ---------------------------------------------------------------------------
__global__ __launch_bounds__(256) void triplane_sample_chw(
    const float* __restrict__ x, const float* __restrict__ p0,
    const float* __restrict__ p1, const float* __restrict__ p2,
    float* __restrict__ out, int npts)
{
    int gid = blockIdx.x * 256 + threadIdx.x;
    int b = gid >> 5;
    int c = gid & 31;
    if (b >= npts) return;

    float c0 = x[b * 3 + 0], c1 = x[b * 3 + 1], c2 = x[b * 3 + 2];
    const float gxs[3] = { c0, c0, c1 };
    const float gys[3] = { c1, c2, c2 };
    const float* planes[3] = { p0, p1, p2 };

    float acc = 1.f;
    #pragma unroll
    for (int pl = 0; pl < 3; ++pl) {
        float ix = fmaf(gxs[pl], 255.5f, 255.5f);
        float iy = fmaf(gys[pl], 255.5f, 255.5f);
        float xf = floorf(ix), yf = floorf(iy);
        float wx = ix - xf,  wy = iy - yf;
        int x0 = min(max((int)xf, 0), RES - 2);
        int y0 = min(max((int)yf, 0), RES - 2);

        const float* base = planes[pl] + (size_t)c * HW + (size_t)y0 * RES + x0;
        float v00 = base[0], v01 = base[1], v10 = base[RES], v11 = base[RES + 1];

        float omx = 1.f - wx, omy = 1.f - wy;
        acc *= fmaf(v00, omx * omy, fmaf(v01, wx * omy,
               fmaf(v10, omx * wy, v11 * (wx * wy))));
    }
    out[(size_t)b * NCH + c] = acc;
}

extern "C" void kernel_launch(void* const* d_in, const int* in_sizes, int n_in,
                              void* d_out, int out_size, void* d_ws, size_t ws_size,
                              hipStream_t stream) {
    const float* x  = (const float*)d_in[0];
    const float* p0 = (const float*)d_in[1];
    const float* p1 = (const float*)d_in[2];
    const float* p2 = (const float*)d_in[3];
    float* out = (float*)d_out;
    int npts = in_sizes[0] / 3;

    // workspace layout
    size_t planes_bytes = (size_t)3 * PLANE_H_ELEMS * sizeof(__half);   // 50.3 MB
    size_t sorted_bytes = (size_t)npts * sizeof(float4);                // 32 MB
    size_t hist_bytes   = NBUCKETS * sizeof(unsigned);
    size_t need = planes_bytes + sorted_bytes + 2 * hist_bytes;

    if (ws_size >= need) {
        char* ws = (char*)d_ws;
        __half*   planes_h = (__half*)ws;
        float4*   sorted   = (float4*)(ws + planes_bytes);
        unsigned* hist     = (unsigned*)(ws + planes_bytes + sorted_bytes);
        unsigned* offs     = hist + NBUCKETS;

        zero_hist<<<NBUCKETS / 256, 256, 0, stream>>>(hist);
        transpose_chw_hwc_h<<<3 * 4096, 256, 0, stream>>>(p0, p1, p2,
                                                          (__half2*)planes_h);
        hist_kernel<<<256, 256, 0, stream>>>(x, npts, hist);
        scan_kernel<<<1, 1024, 0, stream>>>(hist, offs);
        scatter_kernel<<<(npts + 255) / 256, 256, 0, stream>>>(x, npts, offs, sorted);

        int nchunks = (npts + 63) / 64;       // 64 points per block, 2 per thread
        int nb_q = nchunks / 8, nb_r = nchunks & 7;
        sample_sorted_h2<<<nchunks, 256, 0, stream>>>(sorted, planes_h, out, npts, nb_q, nb_r);
    } else {
        long long nthreads = (long long)npts * 32;
        int blocks = (int)((nthreads + 255) / 256);
        triplane_sample_chw<<<blocks, 256, 0, stream>>>(x, p0, p1, p2, out, npts);
    }
}